// Round 10
// baseline (357.953 us; speedup 1.0000x reference)
//
#include <hip/hip_runtime.h>

// VQ-VAE VectorQuantizer: x[32,256,32,32] f32, codebook[1024,256] f32
// out = [loss(1) | quantized[32,256,32,32] | onehot[32768,1024] | idx[32768]] f32
//
// R19: (a) vq_main XCD swizzle (T1): bid -> (kc,mt) remapped so all 8
//     kc-blocks sharing a token tile mt land on the SAME XCD (g%8 == mt%8)
//     -> X fragment re-reads become L2-hits instead of L3/HBM traffic.
//     Bijective permutation (2048%8==0), output slots unchanged ->
//     bit-identical.
// (b) vq_refine batches 4 tokens per block iteration: 4 named fp64
//     accumulators (static indexing, rule #20), cbT element read once per
//     4 tokens (L2 traffic /4) + 4-way fp64 ILP. Same ascending-d fma
//     order per token -> bit-identical re-decision.
// vq_main inner loop frozen at R17 (asm-load 2-deep ping-pong, counted
// vmcnt). R18: cbT transpose in epi; prep unroll 8. R17: epi loss = sum of
// best distances (fp64, W_LOSS double).

typedef short bf16x8 __attribute__((ext_vector_type(8)));
typedef float f32x4  __attribute__((ext_vector_type(4)));

#define K_EMB 1024
#define D_EMB 256
#define HW_SZ 1024
#define CHW   (D_EMB * HW_SZ)   // 262144

#define O_QUANT 1LL
#define O_ENC   8388609LL
#define O_IDX   41943041LL
// 16B-aligned float index inside the one-hot region; holds Xh/Xl bf16 planes
// (16MB each) between vq_prep and vq_main. vq_epi overwrites the region.
#define O_SCRATCH 8388612LL
#define XPLANE_USHORTS 8388608   // 32768 tok * 256 d

// ws layout in float slots (~5.5 MB total)
#define W_LOSS  0                         // double (slots 0-1)
#define W_CNT   2
#define W_ENORM 16
#define W_A     1056                      // + 32768
#define W_EH    33824                     // ushort[32][1024][8] = 131072 floats
#define W_EL    164896                    // ushort[32][1024][8]
#define W_CBT   33824                     // cbT[256][1024] f32, ALIASES Eh/El
                                          // (dead after vq_main; written by
                                          // vq_epi, read by vq_refine)
#define W_V1    295968                    // + 262144 (8 chunks x 32768 tok)
#define W_V2    558112                    // + 262144
#define W_I1    820256                    // + 262144 (int)
#define W_FLAGS 1082400                   // + 32768 (int)

#define FLAG_EPS 6.5e-5f   // 2 ulps at mag 512: covers 1-ulp-per-value drift

__device__ __forceinline__ unsigned bf16rne(float f) {
    const unsigned u = __float_as_uint(f);
    return (u + 0x7FFFu + ((u >> 16) & 1u)) >> 16;
}

// inline-asm 16B load: invisible to LLVM's load-sinking -> stays where issued
template<int OFF>
__device__ __forceinline__ bf16x8 ld128(const unsigned short* p) {
    bf16x8 r;
    asm volatile("global_load_dwordx4 %0, %1, off offset:%2"
                 : "=&v"(r) : "v"(p), "i"(OFF));
    return r;
}
#define VMWAIT16 asm volatile("s_waitcnt vmcnt(16)")
#define VMWAIT0  asm volatile("s_waitcnt vmcnt(0)")
#define SB0 __builtin_amdgcn_sched_barrier(0)

// ---------------------------------------------------------------- prep ------
// blocks 0..63: eNorm (EXACT R5-R9 order) + Eh/El bf16-split planes in
// octet-major [d/8][cand][8] layout + zeroing.
// blocks 64..191: A[n] = ||x_n||^2 serial fmaf ascending c (BIT-IDENTICAL to
// R3-R9's proven order), one thread per token, fused with the Xh/Xl bf16
// split planes written octet-major [d/8][tok][8] into out-scratch.
__global__ __launch_bounds__(256) void vq_prep(const float* __restrict__ cb,
                                               const float* __restrict__ x,
                                               float* __restrict__ ws,
                                               float* __restrict__ out) {
    const int t = threadIdx.x;
    if (blockIdx.x < 64) {
        __shared__ float tile[256][17];
        const int k0 = blockIdx.x * 16;
        #pragma unroll
        for (int i = 0; i < 16; ++i)
            tile[t][i] = cb[(size_t)(k0 + i) * D_EMB + t];   // coalesced
        __syncthreads();
        {   // eNorm: 4 rows/wave, 16 lanes x 16 serial d's + shfl tree
            const int i = t >> 4, j = t & 15;
            float s = 0.0f;
            #pragma unroll
            for (int m = 0; m < 16; ++m) {
                const float v = tile[j * 16 + m][i];
                s = fmaf(v, v, s);
            }
            #pragma unroll
            for (int off = 8; off > 0; off >>= 1) s += __shfl_down(s, off);
            if (j == 0) ws[W_ENORM + k0 + i] = s;
        }
        {   // bf16 hi/lo split planes of E, octet-major [d/8][cand][8]
            unsigned short* __restrict__ Ehp = (unsigned short*)(ws + W_EH);
            unsigned short* __restrict__ Elp = (unsigned short*)(ws + W_EL);
            const int oct = t >> 3, d7 = t & 7;
            #pragma unroll
            for (int i = 0; i < 16; ++i) {
                const float v = tile[t][i];
                const unsigned h = bf16rne(v);
                const unsigned l = bf16rne(v - __uint_as_float(h << 16));
                const size_t off = ((size_t)oct * K_EMB + (k0 + i)) * 8 + d7;
                Ehp[off] = (unsigned short)h;
                Elp[off] = (unsigned short)l;
            }
        }
        if (blockIdx.x == 0 && t == 0) *(double*)(ws + W_LOSS) = 0.0;
        if (blockIdx.x == 0 && t == 1) ((int*)ws)[W_CNT] = 0;
    } else {
        const int tile4 = (blockIdx.x - 64) * 4 + (t >> 6);  // 0..511
        const int b     = tile4 >> 4;
        const int hw0   = (tile4 & 15) * 64;
        const int tok   = t & 63;
        const int n     = tile4 * 64 + tok;
        const float* __restrict__ xb = x + (size_t)b * CHW + hw0 + tok;
        unsigned short* __restrict__ XhG =
            (unsigned short*)(out + O_SCRATCH);
        unsigned short* __restrict__ XlG = XhG + XPLANE_USHORTS;
        float a = 0.0f;
        #pragma unroll 8
        for (int c8 = 0; c8 < 32; ++c8) {
            unsigned hh[8], ll[8];
            #pragma unroll
            for (int j = 0; j < 8; ++j) {
                const float v = xb[(size_t)(c8 * 8 + j) * HW_SZ];
                a = fmaf(v, v, a);               // same ascending-c order
                const unsigned h = bf16rne(v);
                hh[j] = h;
                ll[j] = bf16rne(v - __uint_as_float(h << 16));
            }
            uint4 ph, pl;
            ph.x = hh[0] | (hh[1] << 16); ph.y = hh[2] | (hh[3] << 16);
            ph.z = hh[4] | (hh[5] << 16); ph.w = hh[6] | (hh[7] << 16);
            pl.x = ll[0] | (ll[1] << 16); pl.y = ll[2] | (ll[3] << 16);
            pl.z = ll[4] | (ll[5] << 16); pl.w = ll[6] | (ll[7] << 16);
            *(uint4*)&XhG[((size_t)c8 * 32768 + n) * 8] = ph;
            *(uint4*)&XlG[((size_t)c8 * 32768 + n) * 8] = pl;
        }
        ws[W_A + n] = a;
    }
}

// ---------------------------------------------------------------- main ------
// Block: 128 tok x 128 cand (kc chunk 0..7), K=256 in 8 BK=32 iters.
// Wave quadrants 64x64; per wave 4x4 mfma_f32_16x16x32_bf16 tiles, 3 products.
// R17 inner loop (asm-load 2-deep ping-pong, counted vmcnt) FROZEN.
// R19: XCD swizzle -- g%8 == mt%8 so the 8 kc-blocks of one token tile
// share an XCD's L2 for the X fragments.
__global__ __launch_bounds__(256, 2) void vq_main(float* __restrict__ ws,
                                                  const float* __restrict__ out) {
    const int g   = blockIdx.x;
    const int kc  = (g >> 3) & 7;           // candidate chunk (128 cands)
    const int mt  = (g & 7) | ((g >> 6) << 3);  // token tile (128 tokens)
    const int n0  = mt * 128;
    const int t   = threadIdx.x;
    const int lane = t & 63, w = t >> 6;
    const int l15 = lane & 15, q = lane >> 4;
    const int tokB  = (w & 1) * 64;
    const int candB = (w >> 1) * 64;
    const int cg    = w >> 1;

    __shared__ float mv1[2][128], mv2[2][128];
    __shared__ int   mi1[2][128];

    const unsigned short* __restrict__ XhG =
        (const unsigned short*)(out + O_SCRATCH);
    const unsigned short* __restrict__ XlG = XhG + XPLANE_USHORTS;
    const unsigned short* __restrict__ EhG = (const unsigned short*)(ws + W_EH);
    const unsigned short* __restrict__ ElG = (const unsigned short*)(ws + W_EL);

    f32x4 acc[4][4];
    #pragma unroll
    for (int mi = 0; mi < 4; ++mi)
        #pragma unroll
        for (int ni = 0; ni < 4; ++ni) acc[mi][ni] = (f32x4){0.f, 0.f, 0.f, 0.f};

    // per-lane fragment base offsets (ushort units); rows are 8 ushorts = 16B
    const size_t xoff = ((size_t)q * 32768 + n0 + tokB + l15) * 8;
    const size_t eoff = ((size_t)q * 1024 + (size_t)kc * 128 + candB + l15) * 8;

    // two named fragment sets (ping-pong)
    bf16x8 ahA[4], alA[4], bhA[4], blA[4];
    bf16x8 ahB[4], alB[4], bhB[4], blB[4];

    auto LD = [&](bf16x8* ah, bf16x8* al, bf16x8* bh, bf16x8* bl, int kt) {
        const unsigned short* ph = XhG + xoff + (size_t)kt * (4 * 32768 * 8);
        const unsigned short* pl = XlG + xoff + (size_t)kt * (4 * 32768 * 8);
        const unsigned short* qh = EhG + eoff + (size_t)kt * (4 * 1024 * 8);
        const unsigned short* ql = ElG + eoff + (size_t)kt * (4 * 1024 * 8);
        ah[0] = ld128<0>(ph);   ah[1] = ld128<256>(ph);
        ah[2] = ld128<512>(ph); ah[3] = ld128<768>(ph);
        al[0] = ld128<0>(pl);   al[1] = ld128<256>(pl);
        al[2] = ld128<512>(pl); al[3] = ld128<768>(pl);
        bh[0] = ld128<0>(qh);   bh[1] = ld128<256>(qh);
        bh[2] = ld128<512>(qh); bh[3] = ld128<768>(qh);
        bl[0] = ld128<0>(ql);   bl[1] = ld128<256>(ql);
        bl[2] = ld128<512>(ql); bl[3] = ld128<768>(ql);
    };
    auto MMA = [&](const bf16x8* ah, const bf16x8* al,
                   const bf16x8* bh, const bf16x8* bl) {
        #pragma unroll
        for (int mi = 0; mi < 4; ++mi)
            #pragma unroll
            for (int ni = 0; ni < 4; ++ni) {
                acc[mi][ni] = __builtin_amdgcn_mfma_f32_16x16x32_bf16(
                    ah[mi], bh[ni], acc[mi][ni], 0, 0, 0);
                acc[mi][ni] = __builtin_amdgcn_mfma_f32_16x16x32_bf16(
                    ah[mi], bl[ni], acc[mi][ni], 0, 0, 0);
                acc[mi][ni] = __builtin_amdgcn_mfma_f32_16x16x32_bf16(
                    al[mi], bh[ni], acc[mi][ni], 0, 0, 0);
            }
    };

    LD(ahA, alA, bhA, blA, 0);               // prologue: 16 in flight
    #pragma unroll
    for (int kt = 0; kt < 8; kt += 2) {
        LD(ahB, alB, bhB, blB, kt + 1);      // 32 in flight
        VMWAIT16; SB0;                       // A(kt) complete, B in flight
        MMA(ahA, alA, bhA, blA); SB0;        // compute even kt
        if (kt + 2 < 8) {
            LD(ahA, alA, bhA, blA, kt + 2);  // 32 in flight
            VMWAIT16;                        // B(kt+1) complete
        } else {
            VMWAIT0;                         // last pair: drain
        }
        SB0;
        MMA(ahB, alB, bhB, blB); SB0;        // compute odd kt
    }

    // epilogue: r = fl(fl(A+B)-2D'); per-lane top-2 over ni, xor-butterfly
    // over l15, then 2-half merge (first-index ties preserved throughout).
    float env[4];
    #pragma unroll
    for (int ni = 0; ni < 4; ++ni)
        env[ni] = ws[W_ENORM + kc * 128 + candB + ni * 16 + l15];
    #pragma unroll
    for (int mi = 0; mi < 4; ++mi) {
        const f32x4 A4 = *(const f32x4*)&ws[W_A + n0 + tokB + mi * 16 + q * 4];
        #pragma unroll
        for (int r = 0; r < 4; ++r) {
            const float a = A4[r];
            float v1 = 3.4e38f, v2 = 3.4e38f;
            int i1 = 0;
            #pragma unroll
            for (int ni = 0; ni < 4; ++ni) {   // ascending cand id
                const float vv = __fsub_rn(__fadd_rn(a, env[ni]),
                                           __fmul_rn(2.0f, acc[mi][ni][r]));
                const int id = kc * 128 + candB + ni * 16 + l15;
                if (vv < v1) { v2 = v1; v1 = vv; i1 = id; }
                else if (vv < v2) { v2 = vv; }
            }
            #pragma unroll
            for (int s = 1; s < 16; s <<= 1) {
                const float ov1 = __shfl_xor(v1, s);
                const float ov2 = __shfl_xor(v2, s);
                const int   oi1 = __shfl_xor(i1, s);
                const bool owin = (ov1 < v1) || (ov1 == v1 && oi1 < i1);
                const float lose = owin ? v1 : ov1;
                const float wsec = owin ? ov2 : v2;
                v1 = owin ? ov1 : v1;
                i1 = owin ? oi1 : i1;
                v2 = fminf(lose, wsec);
            }
            if (l15 == 0) {
                const int tok = tokB + mi * 16 + q * 4 + r;
                mv1[cg][tok] = v1;
                mv2[cg][tok] = v2;
                mi1[cg][tok] = i1;
            }
        }
    }
    __syncthreads();
    if (t < 128) {   // merge the 2 cand-halves (cg0 ids < cg1 ids on ties)
        const float a1 = mv1[0][t], a2 = mv2[0][t];
        const float b1 = mv1[1][t], b2 = mv2[1][t];
        const int   ia = mi1[0][t], ib = mi1[1][t];
        const bool bwin = (b1 < a1);        // tie -> a (smaller ids) wins
        const float best = bwin ? b1 : a1;
        const int   bi   = bwin ? ib : ia;
        const float sec  = fminf(bwin ? a1 : b1, bwin ? b2 : a2);
        const int slot = kc * 32768 + n0 + t;
        ws[W_V1 + slot] = best;
        ws[W_V2 + slot] = sec;
        ((int*)ws)[W_I1 + slot] = bi;
    }
}

// ---------------------------------------------------------------- epi -------
// blocks 0..511: merge 8 chunk top-2s, flag near-ties, write idx + one-hot +
// quantized; loss = sum of best distances (fp64 acc).
// blocks 512..575: write transposed fp32 codebook cbT[d][k] into ws[W_CBT]
// (Eh/El region, dead after vq_main) for vq_refine's coalesced reads.
__global__ __launch_bounds__(256) void vq_epi(const float* __restrict__ x,
                                              const float* __restrict__ cb,
                                              float* __restrict__ ws,
                                              float* __restrict__ out) {
    (void)x;
    const int tile = blockIdx.x;
    const int t    = threadIdx.x;

    if (tile >= 512) {                      // cb transpose: 16 cands/block
        __shared__ float tt[16][257];
        const int k0 = (tile - 512) * 16;
        #pragma unroll
        for (int i = 0; i < 16; ++i)
            tt[i][t] = cb[(size_t)(k0 + i) * D_EMB + t];   // coalesced
        __syncthreads();
        float* __restrict__ cbT = ws + W_CBT;
        const int j = t & 15;               // cand within chunk
        #pragma unroll
        for (int dd = t >> 4; dd < 256; dd += 16)
            cbT[(size_t)dd * K_EMB + k0 + j] = tt[j][dd];
        return;
    }

    const int b    = tile >> 4;
    const int hw0  = (tile & 15) * 64;
    const int n0   = tile * 64;

    __shared__ float qs[32 * 65];           // 8.3KB (bank-conflict pad)
    __shared__ int   idxS[64];

    if (t < 64) {
        float best = 3.4e38f, sec = 3.4e38f, bv2 = 3.4e38f;
        int bi = 0;
        for (int kc = 0; kc < 8; ++kc) {    // ascending kc => ascending ids
            const int slot = kc * 32768 + n0 + t;
            const float v  = ws[W_V1 + slot];
            const float v2 = ws[W_V2 + slot];
            const int  id  = ((const int*)ws)[W_I1 + slot];
            if (v < best || (v == best && id < bi)) {
                if (best < sec) sec = best;
                best = v; bi = id; bv2 = v2;
            } else if (v < sec) { sec = v; }
        }
        if (bv2 < sec) sec = bv2;
        idxS[t] = bi;
        out[O_IDX + n0 + t] = (float)bi;
        if (sec - best <= FLAG_EPS) {       // near-tie: fp64 re-decision
            const int p = atomicAdd((int*)ws + W_CNT, 1);
            ((int*)ws)[W_FLAGS + p] = n0 + t;
        }
        // loss partial: sum of best distances over this tile (wave 0 only)
        float ls = best;
        #pragma unroll
        for (int off = 32; off > 0; off >>= 1) ls += __shfl_down(ls, off);
        if (t == 0) atomicAdd((double*)(ws + W_LOSS), (double)ls);
    }
    __syncthreads();

    // one-hot: 64 rows x 1024 cols, one float4 per thread per row
    {
        float* encp = out + O_ENC + (size_t)n0 * K_EMB;
        const int c0 = t * 4;
        for (int row = 0; row < 64; ++row) {
            const int id = idxS[row];
            f32x4 ev;
            ev[0] = (c0     == id) ? 1.0f : 0.0f;
            ev[1] = (c0 + 1 == id) ? 1.0f : 0.0f;
            ev[2] = (c0 + 2 == id) ? 1.0f : 0.0f;
            ev[3] = (c0 + 3 == id) ? 1.0f : 0.0f;
            *(f32x4*)&encp[row * K_EMB + c0] = ev;
        }
    }

    // quantized (= straight-through value)
    for (int cc = 0; cc < 256; cc += 32) {
        __syncthreads();
        {   // gather 64 codebook rows' 32-col slice into LDS, transposed
            const int r = t >> 2, part = t & 3;
            const float* crow = cb + (size_t)idxS[r] * D_EMB + cc + part * 8;
            const float4 q0 = *(const float4*)(crow);
            const float4 q1 = *(const float4*)(crow + 4);
            const int cb0 = part * 8;
            qs[(cb0 + 0) * 65 + r] = q0.x; qs[(cb0 + 1) * 65 + r] = q0.y;
            qs[(cb0 + 2) * 65 + r] = q0.z; qs[(cb0 + 3) * 65 + r] = q0.w;
            qs[(cb0 + 4) * 65 + r] = q1.x; qs[(cb0 + 5) * 65 + r] = q1.y;
            qs[(cb0 + 6) * 65 + r] = q1.z; qs[(cb0 + 7) * 65 + r] = q1.w;
        }
        __syncthreads();
        const int tok = t & 63, cgr = t >> 6;
        #pragma unroll
        for (int m = 0; m < 8; ++m) {
            const int cl = cgr * 8 + m;
            const int c  = cc + cl;
            out[O_QUANT + (size_t)b * CHW + (size_t)c * HW_SZ + hw0 + tok] =
                qs[cl * 65 + tok];
        }
    }
}

// --------------------------------------------------------------- refine -----
// R19: FOUR tokens per block-iteration, one candidate per thread (1024):
// cbT element read once per 4 tokens (L2 traffic /4), 4 named fp64
// accumulators (static indexing). Per token: fp64 dot rounded to fp32 via
// same ascending-d order -> bit-identical; np op-order fp32 rounding;
// lexicographic (r,k) tree reduce; patch idx/one-hot/quantized.
__global__ __launch_bounds__(1024) void vq_refine(const float* __restrict__ x,
                                                  const float* __restrict__ cb,
                                                  const float* __restrict__ ws,
                                                  float* __restrict__ out) {
    if (blockIdx.x == 0 && threadIdx.x == 0)
        out[0] = (float)(1.25 * (*(const double*)(ws + W_LOSS)) / 8388608.0);
    __shared__ float xs4[4][256];
    __shared__ float rS[1024];
    __shared__ int   kS[1024];
    __shared__ int   nArr[4];
    int cnt = ((const int*)ws)[W_CNT];
    if (cnt > 32768) cnt = 32768;
    const int t = threadIdx.x;
    const float* __restrict__ eN  = ws + W_ENORM;
    const float* __restrict__ cbT = ws + W_CBT;

    for (int f0 = blockIdx.x * 4; f0 < cnt; f0 += gridDim.x * 4) {
        const int nv = (cnt - f0 < 4) ? (cnt - f0) : 4;
        __syncthreads();   // protect xs4/rS/kS reuse across iterations
        if (t < 256) {
            for (int j = 0; j < nv; ++j) {
                const int n = ((const int*)ws)[W_FLAGS + f0 + j];
                xs4[j][t] = x[(size_t)(n >> 10) * CHW +
                              (size_t)t * HW_SZ + (n & 1023)];
            }
        }
        if (t < 4) nArr[t] = (t < nv) ? ((const int*)ws)[W_FLAGS + f0 + t] : 0;
        __syncthreads();

        double d0 = 0.0, d1 = 0.0, d2 = 0.0, d3 = 0.0;
        #pragma unroll 4
        for (int d = 0; d < 256; ++d) {
            const double c = (double)cbT[(size_t)d * K_EMB + t];
            d0 = fma(c, (double)xs4[0][d], d0);
            d1 = fma(c, (double)xs4[1][d], d1);
            d2 = fma(c, (double)xs4[2][d], d2);
            d3 = fma(c, (double)xs4[3][d], d3);
        }

        // process token j (serialized; barriers protect rS/kS)
        auto PROC = [&](int j, double d64) {
            const int n = nArr[j];
            __syncthreads();
            const float A = ws[W_A + n];    // same A as vq_main used
            const float M  = (float)d64;    // ideal np matmul output
            const float T1 = __fadd_rn(A, eN[t]);
            rS[t] = __fsub_rn(T1, __fmul_rn(2.0f, M));
            kS[t] = t;
            __syncthreads();
            for (int off = 512; off > 0; off >>= 1) {
                if (t < off) {
                    const float r = rS[t + off]; const int id = kS[t + off];
                    if (r < rS[t] || (r == rS[t] && id < kS[t])) {
                        rS[t] = r; kS[t] = id;  // lexicographic (r, k)
                    }
                }
                __syncthreads();
            }
            const int newIdx = kS[0];
            if (t == 0) {
                const int oldIdx = (int)out[O_IDX + n];
                out[O_IDX + n] = (float)newIdx;
                out[O_ENC + (size_t)n * K_EMB + oldIdx] = 0.0f;  // same thread:
                out[O_ENC + (size_t)n * K_EMB + newIdx] = 1.0f;  // ordered
            }
            if (t < 256)
                out[O_QUANT + (size_t)(n >> 10) * CHW +
                    (size_t)t * HW_SZ + (n & 1023)] =
                    cb[(size_t)newIdx * D_EMB + t];
        };
        if (nv > 0) PROC(0, d0);
        if (nv > 1) PROC(1, d1);
        if (nv > 2) PROC(2, d2);
        if (nv > 3) PROC(3, d3);
    }
}

extern "C" void kernel_launch(void* const* d_in, const int* in_sizes, int n_in,
                              void* d_out, int out_size, void* d_ws, size_t ws_size,
                              hipStream_t stream) {
    (void)in_sizes; (void)n_in; (void)out_size; (void)ws_size;
    const float* x  = (const float*)d_in[0];
    const float* cb = (const float*)d_in[1];
    float* out = (float*)d_out;
    float* ws  = (float*)d_ws;
    hipLaunchKernelGGL(vq_prep,   dim3(192),  dim3(256),  0, stream, cb, x, ws, out);
    hipLaunchKernelGGL(vq_main,   dim3(2048), dim3(256),  0, stream, ws, out);
    hipLaunchKernelGGL(vq_epi,    dim3(576),  dim3(256),  0, stream, x, cb, ws, out);
    hipLaunchKernelGGL(vq_refine, dim3(256),  dim3(1024), 0, stream, x, cb, ws, out);
}

// Round 11
// 348.463 us; speedup vs baseline: 1.0272x; 1.0272x over previous
//
#include <hip/hip_runtime.h>

// VQ-VAE VectorQuantizer: x[32,256,32,32] f32, codebook[1024,256] f32
// out = [loss(1) | quantized[32,256,32,32] | onehot[32768,1024] | idx[32768]] f32
//
// R20: periphery de-serialization (R18/R19 periphery tweaks were neutral ->
// the cost is phase serialization, not traffic):
// (a) vq_epi: one-hot hoisted to its OWN 512 blocks (grid 576->1088) that
//     re-derive the winning idx from ws V1/I1 with the identical tie-rule
//     scan (merge-lite; vq_main outputs complete -> race-free). Merge
//     blocks keep flags+loss+idx+quantized only. 2x parallelism, one-hot
//     stores overlap quantized stores.
// (b) vq_refine: revert R19's 4-token batching (cbT is L2-resident; the
//     4 serialized reduce passes cost more than the reuse saved). One
//     token per block, 1024 blocks, coalesced cbT -- same products, same
//     ascending-d fp64 order -> bit-identical.
// (c) vq_prep A-pass: unroll 8->16 (latency-bound at 512 waves; ~2x
//     outstanding bytes). Same serial fmaf order -> A bit-identical.
// vq_main frozen at R17/R19 (asm 2-deep ping-pong + XCD swizzle).

typedef short bf16x8 __attribute__((ext_vector_type(8)));
typedef float f32x4  __attribute__((ext_vector_type(4)));

#define K_EMB 1024
#define D_EMB 256
#define HW_SZ 1024
#define CHW   (D_EMB * HW_SZ)   // 262144

#define O_QUANT 1LL
#define O_ENC   8388609LL
#define O_IDX   41943041LL
// 16B-aligned float index inside the one-hot region; holds Xh/Xl bf16 planes
// (16MB each) between vq_prep and vq_main. vq_epi overwrites the region.
#define O_SCRATCH 8388612LL
#define XPLANE_USHORTS 8388608   // 32768 tok * 256 d

// ws layout in float slots (~5.5 MB total)
#define W_LOSS  0                         // double (slots 0-1)
#define W_CNT   2
#define W_ENORM 16
#define W_A     1056                      // + 32768
#define W_EH    33824                     // ushort[32][1024][8] = 131072 floats
#define W_EL    164896                    // ushort[32][1024][8]
#define W_CBT   33824                     // cbT[256][1024] f32, ALIASES Eh/El
                                          // (dead after vq_main; written by
                                          // vq_epi, read by vq_refine)
#define W_V1    295968                    // + 262144 (8 chunks x 32768 tok)
#define W_V2    558112                    // + 262144
#define W_I1    820256                    // + 262144 (int)
#define W_FLAGS 1082400                   // + 32768 (int)

#define FLAG_EPS 6.5e-5f   // 2 ulps at mag 512: covers 1-ulp-per-value drift

__device__ __forceinline__ unsigned bf16rne(float f) {
    const unsigned u = __float_as_uint(f);
    return (u + 0x7FFFu + ((u >> 16) & 1u)) >> 16;
}

// inline-asm 16B load: invisible to LLVM's load-sinking -> stays where issued
template<int OFF>
__device__ __forceinline__ bf16x8 ld128(const unsigned short* p) {
    bf16x8 r;
    asm volatile("global_load_dwordx4 %0, %1, off offset:%2"
                 : "=&v"(r) : "v"(p), "i"(OFF));
    return r;
}
#define VMWAIT16 asm volatile("s_waitcnt vmcnt(16)")
#define VMWAIT0  asm volatile("s_waitcnt vmcnt(0)")
#define SB0 __builtin_amdgcn_sched_barrier(0)

// ---------------------------------------------------------------- prep ------
// blocks 0..63: eNorm (EXACT R5-R9 order) + Eh/El bf16-split planes in
// octet-major [d/8][cand][8] layout + zeroing.
// blocks 64..191: A[n] = ||x_n||^2 serial fmaf ascending c (BIT-IDENTICAL to
// R3-R9's proven order), one thread per token, fused with the Xh/Xl bf16
// split planes written octet-major [d/8][tok][8] into out-scratch.
__global__ __launch_bounds__(256) void vq_prep(const float* __restrict__ cb,
                                               const float* __restrict__ x,
                                               float* __restrict__ ws,
                                               float* __restrict__ out) {
    const int t = threadIdx.x;
    if (blockIdx.x < 64) {
        __shared__ float tile[256][17];
        const int k0 = blockIdx.x * 16;
        #pragma unroll
        for (int i = 0; i < 16; ++i)
            tile[t][i] = cb[(size_t)(k0 + i) * D_EMB + t];   // coalesced
        __syncthreads();
        {   // eNorm: 4 rows/wave, 16 lanes x 16 serial d's + shfl tree
            const int i = t >> 4, j = t & 15;
            float s = 0.0f;
            #pragma unroll
            for (int m = 0; m < 16; ++m) {
                const float v = tile[j * 16 + m][i];
                s = fmaf(v, v, s);
            }
            #pragma unroll
            for (int off = 8; off > 0; off >>= 1) s += __shfl_down(s, off);
            if (j == 0) ws[W_ENORM + k0 + i] = s;
        }
        {   // bf16 hi/lo split planes of E, octet-major [d/8][cand][8]
            unsigned short* __restrict__ Ehp = (unsigned short*)(ws + W_EH);
            unsigned short* __restrict__ Elp = (unsigned short*)(ws + W_EL);
            const int oct = t >> 3, d7 = t & 7;
            #pragma unroll
            for (int i = 0; i < 16; ++i) {
                const float v = tile[t][i];
                const unsigned h = bf16rne(v);
                const unsigned l = bf16rne(v - __uint_as_float(h << 16));
                const size_t off = ((size_t)oct * K_EMB + (k0 + i)) * 8 + d7;
                Ehp[off] = (unsigned short)h;
                Elp[off] = (unsigned short)l;
            }
        }
        if (blockIdx.x == 0 && t == 0) *(double*)(ws + W_LOSS) = 0.0;
        if (blockIdx.x == 0 && t == 1) ((int*)ws)[W_CNT] = 0;
    } else {
        const int tile4 = (blockIdx.x - 64) * 4 + (t >> 6);  // 0..511
        const int b     = tile4 >> 4;
        const int hw0   = (tile4 & 15) * 64;
        const int tok   = t & 63;
        const int n     = tile4 * 64 + tok;
        const float* __restrict__ xb = x + (size_t)b * CHW + hw0 + tok;
        unsigned short* __restrict__ XhG =
            (unsigned short*)(out + O_SCRATCH);
        unsigned short* __restrict__ XlG = XhG + XPLANE_USHORTS;
        float a = 0.0f;
        #pragma unroll 16
        for (int c8 = 0; c8 < 32; ++c8) {
            unsigned hh[8], ll[8];
            #pragma unroll
            for (int j = 0; j < 8; ++j) {
                const float v = xb[(size_t)(c8 * 8 + j) * HW_SZ];
                a = fmaf(v, v, a);               // same ascending-c order
                const unsigned h = bf16rne(v);
                hh[j] = h;
                ll[j] = bf16rne(v - __uint_as_float(h << 16));
            }
            uint4 ph, pl;
            ph.x = hh[0] | (hh[1] << 16); ph.y = hh[2] | (hh[3] << 16);
            ph.z = hh[4] | (hh[5] << 16); ph.w = hh[6] | (hh[7] << 16);
            pl.x = ll[0] | (ll[1] << 16); pl.y = ll[2] | (ll[3] << 16);
            pl.z = ll[4] | (ll[5] << 16); pl.w = ll[6] | (ll[7] << 16);
            *(uint4*)&XhG[((size_t)c8 * 32768 + n) * 8] = ph;
            *(uint4*)&XlG[((size_t)c8 * 32768 + n) * 8] = pl;
        }
        ws[W_A + n] = a;
    }
}

// ---------------------------------------------------------------- main ------
// Block: 128 tok x 128 cand (kc chunk 0..7), K=256 in 8 BK=32 iters.
// Wave quadrants 64x64; per wave 4x4 mfma_f32_16x16x32_bf16 tiles, 3 products.
// R17 inner loop (asm-load 2-deep ping-pong, counted vmcnt) FROZEN.
// R19 XCD swizzle kept (g%8 == mt%8).
__global__ __launch_bounds__(256, 2) void vq_main(float* __restrict__ ws,
                                                  const float* __restrict__ out) {
    const int g   = blockIdx.x;
    const int kc  = (g >> 3) & 7;           // candidate chunk (128 cands)
    const int mt  = (g & 7) | ((g >> 6) << 3);  // token tile (128 tokens)
    const int n0  = mt * 128;
    const int t   = threadIdx.x;
    const int lane = t & 63, w = t >> 6;
    const int l15 = lane & 15, q = lane >> 4;
    const int tokB  = (w & 1) * 64;
    const int candB = (w >> 1) * 64;
    const int cg    = w >> 1;

    __shared__ float mv1[2][128], mv2[2][128];
    __shared__ int   mi1[2][128];

    const unsigned short* __restrict__ XhG =
        (const unsigned short*)(out + O_SCRATCH);
    const unsigned short* __restrict__ XlG = XhG + XPLANE_USHORTS;
    const unsigned short* __restrict__ EhG = (const unsigned short*)(ws + W_EH);
    const unsigned short* __restrict__ ElG = (const unsigned short*)(ws + W_EL);

    f32x4 acc[4][4];
    #pragma unroll
    for (int mi = 0; mi < 4; ++mi)
        #pragma unroll
        for (int ni = 0; ni < 4; ++ni) acc[mi][ni] = (f32x4){0.f, 0.f, 0.f, 0.f};

    // per-lane fragment base offsets (ushort units); rows are 8 ushorts = 16B
    const size_t xoff = ((size_t)q * 32768 + n0 + tokB + l15) * 8;
    const size_t eoff = ((size_t)q * 1024 + (size_t)kc * 128 + candB + l15) * 8;

    // two named fragment sets (ping-pong)
    bf16x8 ahA[4], alA[4], bhA[4], blA[4];
    bf16x8 ahB[4], alB[4], bhB[4], blB[4];

    auto LD = [&](bf16x8* ah, bf16x8* al, bf16x8* bh, bf16x8* bl, int kt) {
        const unsigned short* ph = XhG + xoff + (size_t)kt * (4 * 32768 * 8);
        const unsigned short* pl = XlG + xoff + (size_t)kt * (4 * 32768 * 8);
        const unsigned short* qh = EhG + eoff + (size_t)kt * (4 * 1024 * 8);
        const unsigned short* ql = ElG + eoff + (size_t)kt * (4 * 1024 * 8);
        ah[0] = ld128<0>(ph);   ah[1] = ld128<256>(ph);
        ah[2] = ld128<512>(ph); ah[3] = ld128<768>(ph);
        al[0] = ld128<0>(pl);   al[1] = ld128<256>(pl);
        al[2] = ld128<512>(pl); al[3] = ld128<768>(pl);
        bh[0] = ld128<0>(qh);   bh[1] = ld128<256>(qh);
        bh[2] = ld128<512>(qh); bh[3] = ld128<768>(qh);
        bl[0] = ld128<0>(ql);   bl[1] = ld128<256>(ql);
        bl[2] = ld128<512>(ql); bl[3] = ld128<768>(ql);
    };
    auto MMA = [&](const bf16x8* ah, const bf16x8* al,
                   const bf16x8* bh, const bf16x8* bl) {
        #pragma unroll
        for (int mi = 0; mi < 4; ++mi)
            #pragma unroll
            for (int ni = 0; ni < 4; ++ni) {
                acc[mi][ni] = __builtin_amdgcn_mfma_f32_16x16x32_bf16(
                    ah[mi], bh[ni], acc[mi][ni], 0, 0, 0);
                acc[mi][ni] = __builtin_amdgcn_mfma_f32_16x16x32_bf16(
                    ah[mi], bl[ni], acc[mi][ni], 0, 0, 0);
                acc[mi][ni] = __builtin_amdgcn_mfma_f32_16x16x32_bf16(
                    al[mi], bh[ni], acc[mi][ni], 0, 0, 0);
            }
    };

    LD(ahA, alA, bhA, blA, 0);               // prologue: 16 in flight
    #pragma unroll
    for (int kt = 0; kt < 8; kt += 2) {
        LD(ahB, alB, bhB, blB, kt + 1);      // 32 in flight
        VMWAIT16; SB0;                       // A(kt) complete, B in flight
        MMA(ahA, alA, bhA, blA); SB0;        // compute even kt
        if (kt + 2 < 8) {
            LD(ahA, alA, bhA, blA, kt + 2);  // 32 in flight
            VMWAIT16;                        // B(kt+1) complete
        } else {
            VMWAIT0;                         // last pair: drain
        }
        SB0;
        MMA(ahB, alB, bhB, blB); SB0;        // compute odd kt
    }

    // epilogue: r = fl(fl(A+B)-2D'); per-lane top-2 over ni, xor-butterfly
    // over l15, then 2-half merge (first-index ties preserved throughout).
    float env[4];
    #pragma unroll
    for (int ni = 0; ni < 4; ++ni)
        env[ni] = ws[W_ENORM + kc * 128 + candB + ni * 16 + l15];
    #pragma unroll
    for (int mi = 0; mi < 4; ++mi) {
        const f32x4 A4 = *(const f32x4*)&ws[W_A + n0 + tokB + mi * 16 + q * 4];
        #pragma unroll
        for (int r = 0; r < 4; ++r) {
            const float a = A4[r];
            float v1 = 3.4e38f, v2 = 3.4e38f;
            int i1 = 0;
            #pragma unroll
            for (int ni = 0; ni < 4; ++ni) {   // ascending cand id
                const float vv = __fsub_rn(__fadd_rn(a, env[ni]),
                                           __fmul_rn(2.0f, acc[mi][ni][r]));
                const int id = kc * 128 + candB + ni * 16 + l15;
                if (vv < v1) { v2 = v1; v1 = vv; i1 = id; }
                else if (vv < v2) { v2 = vv; }
            }
            #pragma unroll
            for (int s = 1; s < 16; s <<= 1) {
                const float ov1 = __shfl_xor(v1, s);
                const float ov2 = __shfl_xor(v2, s);
                const int   oi1 = __shfl_xor(i1, s);
                const bool owin = (ov1 < v1) || (ov1 == v1 && oi1 < i1);
                const float lose = owin ? v1 : ov1;
                const float wsec = owin ? ov2 : v2;
                v1 = owin ? ov1 : v1;
                i1 = owin ? oi1 : i1;
                v2 = fminf(lose, wsec);
            }
            if (l15 == 0) {
                const int tok = tokB + mi * 16 + q * 4 + r;
                mv1[cg][tok] = v1;
                mv2[cg][tok] = v2;
                mi1[cg][tok] = i1;
            }
        }
    }
    __syncthreads();
    if (t < 128) {   // merge the 2 cand-halves (cg0 ids < cg1 ids on ties)
        const float a1 = mv1[0][t], a2 = mv2[0][t];
        const float b1 = mv1[1][t], b2 = mv2[1][t];
        const int   ia = mi1[0][t], ib = mi1[1][t];
        const bool bwin = (b1 < a1);        // tie -> a (smaller ids) wins
        const float best = bwin ? b1 : a1;
        const int   bi   = bwin ? ib : ia;
        const float sec  = fminf(bwin ? a1 : b1, bwin ? b2 : a2);
        const int slot = kc * 32768 + n0 + t;
        ws[W_V1 + slot] = best;
        ws[W_V2 + slot] = sec;
        ((int*)ws)[W_I1 + slot] = bi;
    }
}

// ---------------------------------------------------------------- epi -------
// blocks 0..511:   merge 8 chunk top-2s (flags + loss + idx) + quantized.
// blocks 512..575: cbT transpose into ws[W_CBT] for vq_refine.
// blocks 576..1087: one-hot, idx re-derived from ws V1/I1 (merge-lite with
//                   identical tie rules; race-free: reads vq_main output).
__global__ __launch_bounds__(256) void vq_epi(const float* __restrict__ x,
                                              const float* __restrict__ cb,
                                              float* __restrict__ ws,
                                              float* __restrict__ out) {
    (void)x;
    const int bid = blockIdx.x;
    const int t   = threadIdx.x;

    if (bid >= 576) {                       // ---- one-hot blocks ----
        const int tile = bid - 576;         // 0..511
        const int n0   = tile * 64;
        __shared__ int idxS[64];
        if (t < 64) {                       // merge-lite: same tie rules
            float best = 3.4e38f;
            int bi = 0;
            for (int kc = 0; kc < 8; ++kc) {
                const int slot = kc * 32768 + n0 + t;
                const float v = ws[W_V1 + slot];
                const int  id = ((const int*)ws)[W_I1 + slot];
                if (v < best || (v == best && id < bi)) { best = v; bi = id; }
            }
            idxS[t] = bi;
        }
        __syncthreads();
        float* encp = out + O_ENC + (size_t)n0 * K_EMB;
        const int c0 = t * 4;
        for (int row = 0; row < 64; ++row) {
            const int id = idxS[row];
            f32x4 ev;
            ev[0] = (c0     == id) ? 1.0f : 0.0f;
            ev[1] = (c0 + 1 == id) ? 1.0f : 0.0f;
            ev[2] = (c0 + 2 == id) ? 1.0f : 0.0f;
            ev[3] = (c0 + 3 == id) ? 1.0f : 0.0f;
            *(f32x4*)&encp[row * K_EMB + c0] = ev;
        }
        return;
    }

    if (bid >= 512) {                       // ---- cbT transpose blocks ----
        __shared__ float tt[16][257];
        const int k0 = (bid - 512) * 16;
        #pragma unroll
        for (int i = 0; i < 16; ++i)
            tt[i][t] = cb[(size_t)(k0 + i) * D_EMB + t];   // coalesced
        __syncthreads();
        float* __restrict__ cbT = ws + W_CBT;
        const int j = t & 15;               // cand within chunk
        #pragma unroll
        for (int dd = t >> 4; dd < 256; dd += 16)
            cbT[(size_t)dd * K_EMB + k0 + j] = tt[j][dd];
        return;
    }

    // ---- merge + quantized blocks ----
    const int tile = bid;                   // 0..511 (64-token tiles)
    const int b    = tile >> 4;
    const int hw0  = (tile & 15) * 64;
    const int n0   = tile * 64;

    __shared__ float qs[32 * 65];           // 8.3KB (bank-conflict pad)
    __shared__ int   idxS[64];

    if (t < 64) {
        float best = 3.4e38f, sec = 3.4e38f, bv2 = 3.4e38f;
        int bi = 0;
        for (int kc = 0; kc < 8; ++kc) {    // ascending kc => ascending ids
            const int slot = kc * 32768 + n0 + t;
            const float v  = ws[W_V1 + slot];
            const float v2 = ws[W_V2 + slot];
            const int  id  = ((const int*)ws)[W_I1 + slot];
            if (v < best || (v == best && id < bi)) {
                if (best < sec) sec = best;
                best = v; bi = id; bv2 = v2;
            } else if (v < sec) { sec = v; }
        }
        if (bv2 < sec) sec = bv2;
        idxS[t] = bi;
        out[O_IDX + n0 + t] = (float)bi;
        if (sec - best <= FLAG_EPS) {       // near-tie: fp64 re-decision
            const int p = atomicAdd((int*)ws + W_CNT, 1);
            ((int*)ws)[W_FLAGS + p] = n0 + t;
        }
        // loss partial: sum of best distances over this tile (wave 0 only)
        float ls = best;
        #pragma unroll
        for (int off = 32; off > 0; off >>= 1) ls += __shfl_down(ls, off);
        if (t == 0) atomicAdd((double*)(ws + W_LOSS), (double)ls);
    }

    // quantized (= straight-through value)
    for (int cc = 0; cc < 256; cc += 32) {
        __syncthreads();
        {   // gather 64 codebook rows' 32-col slice into LDS, transposed
            const int r = t >> 2, part = t & 3;
            const float* crow = cb + (size_t)idxS[r] * D_EMB + cc + part * 8;
            const float4 q0 = *(const float4*)(crow);
            const float4 q1 = *(const float4*)(crow + 4);
            const int cb0 = part * 8;
            qs[(cb0 + 0) * 65 + r] = q0.x; qs[(cb0 + 1) * 65 + r] = q0.y;
            qs[(cb0 + 2) * 65 + r] = q0.z; qs[(cb0 + 3) * 65 + r] = q0.w;
            qs[(cb0 + 4) * 65 + r] = q1.x; qs[(cb0 + 5) * 65 + r] = q1.y;
            qs[(cb0 + 6) * 65 + r] = q1.z; qs[(cb0 + 7) * 65 + r] = q1.w;
        }
        __syncthreads();
        const int tok = t & 63, cgr = t >> 6;
        #pragma unroll
        for (int m = 0; m < 8; ++m) {
            const int cl = cgr * 8 + m;
            const int c  = cc + cl;
            out[O_QUANT + (size_t)b * CHW + (size_t)c * HW_SZ + hw0 + tok] =
                qs[cl * 65 + tok];
        }
    }
}

// --------------------------------------------------------------- refine -----
// R20: back to ONE token per block (R19's 4-batch serialized 4 reduce
// passes for no gain -- cbT is L2-resident). One candidate per thread
// (1024): fp64 dot via coalesced cbT, same ascending-d order ->
// bit-identical; np op-order fp32 rounding; lexicographic (r,k) tree
// reduce; patch idx/one-hot/quantized; writes final loss.
__global__ __launch_bounds__(1024) void vq_refine(const float* __restrict__ x,
                                                  const float* __restrict__ cb,
                                                  const float* __restrict__ ws,
                                                  float* __restrict__ out) {
    if (blockIdx.x == 0 && threadIdx.x == 0)
        out[0] = (float)(1.25 * (*(const double*)(ws + W_LOSS)) / 8388608.0);
    __shared__ float xs[256];
    __shared__ float rS[1024];
    __shared__ int   kS[1024];
    int cnt = ((const int*)ws)[W_CNT];
    if (cnt > 32768) cnt = 32768;
    const int t = threadIdx.x;
    const float* __restrict__ eN  = ws + W_ENORM;
    const float* __restrict__ cbT = ws + W_CBT;
    for (int fi = blockIdx.x; fi < cnt; fi += gridDim.x) {
        const int n  = ((const int*)ws)[W_FLAGS + fi];
        const int b  = n >> 10;
        const int hw = n & 1023;
        __syncthreads();   // protect xs/rS/kS reuse across fi iterations
        if (t < 256) xs[t] = x[(size_t)b * CHW + (size_t)t * HW_SZ + hw];
        __syncthreads();
        const float A = ws[W_A + n];        // same A as vq_main used
        {
            const int k = t;                // one candidate per thread
            double d64 = 0.0;
            #pragma unroll 8
            for (int d = 0; d < 256; ++d)
                d64 = fma((double)cbT[(size_t)d * K_EMB + k],
                          (double)xs[d], d64);
            const float M  = (float)d64;    // ideal np matmul output
            const float T1 = __fadd_rn(A, eN[k]);
            rS[t] = __fsub_rn(T1, __fmul_rn(2.0f, M));
            kS[t] = k;
        }
        __syncthreads();
        for (int off = 512; off > 0; off >>= 1) {
            if (t < off) {
                const float r = rS[t + off]; const int id = kS[t + off];
                if (r < rS[t] || (r == rS[t] && id < kS[t])) {
                    rS[t] = r; kS[t] = id;  // lexicographic (r, k)
                }
            }
            __syncthreads();
        }
        const int newIdx = kS[0];
        if (t == 0) {
            const int oldIdx = (int)out[O_IDX + n];
            out[O_IDX + n] = (float)newIdx;
            out[O_ENC + (size_t)n * K_EMB + oldIdx] = 0.0f;  // same thread:
            out[O_ENC + (size_t)n * K_EMB + newIdx] = 1.0f;  // ordered stores
        }
        if (t < 256)
            out[O_QUANT + (size_t)b * CHW + (size_t)t * HW_SZ + hw] =
                cb[(size_t)newIdx * D_EMB + t];
    }
}

extern "C" void kernel_launch(void* const* d_in, const int* in_sizes, int n_in,
                              void* d_out, int out_size, void* d_ws, size_t ws_size,
                              hipStream_t stream) {
    (void)in_sizes; (void)n_in; (void)out_size; (void)ws_size;
    const float* x  = (const float*)d_in[0];
    const float* cb = (const float*)d_in[1];
    float* out = (float*)d_out;
    float* ws  = (float*)d_ws;
    hipLaunchKernelGGL(vq_prep,   dim3(192),  dim3(256),  0, stream, cb, x, ws, out);
    hipLaunchKernelGGL(vq_main,   dim3(2048), dim3(256),  0, stream, ws, out);
    hipLaunchKernelGGL(vq_epi,    dim3(1088), dim3(256),  0, stream, x, cb, ws, out);
    hipLaunchKernelGGL(vq_refine, dim3(1024), dim3(1024), 0, stream, x, cb, ws, out);
}

// Round 12
// 347.908 us; speedup vs baseline: 1.0289x; 1.0016x over previous
//
#include <hip/hip_runtime.h>

// VQ-VAE VectorQuantizer: x[32,256,32,32] f32, codebook[1024,256] f32
// out = [loss(1) | quantized[32,256,32,32] | onehot[32768,1024] | idx[32768]] f32
//
// R21: single-variable round -- vq_prep x-pass geometry. The 512 serial-A
// waves were packed 4-per-block into 128 blocks -> only half the CUs
// active, 4 heavy waves contending per CU TA queue. Now 256 blocks x 2
// active waves (waves 2-3 exit; no barriers in this family): every CU
// gets 2 waves, half the queue contention, same per-token serial fmaf
// order -> A and planes bit-identical. Everything else frozen at R20.
//
// R20: epi one-hot in own 512 blocks (merge-lite re-derive); refine one
// token/block coalesced cbT; prep unroll 16.
// R19: main XCD swizzle (g%8==mt%8). R17: main asm-load 2-deep ping-pong
// with counted vmcnt; epi loss = sum best distances (fp64, W_LOSS double).

typedef short bf16x8 __attribute__((ext_vector_type(8)));
typedef float f32x4  __attribute__((ext_vector_type(4)));

#define K_EMB 1024
#define D_EMB 256
#define HW_SZ 1024
#define CHW   (D_EMB * HW_SZ)   // 262144

#define O_QUANT 1LL
#define O_ENC   8388609LL
#define O_IDX   41943041LL
// 16B-aligned float index inside the one-hot region; holds Xh/Xl bf16 planes
// (16MB each) between vq_prep and vq_main. vq_epi overwrites the region.
#define O_SCRATCH 8388612LL
#define XPLANE_USHORTS 8388608   // 32768 tok * 256 d

// ws layout in float slots (~5.5 MB total)
#define W_LOSS  0                         // double (slots 0-1)
#define W_CNT   2
#define W_ENORM 16
#define W_A     1056                      // + 32768
#define W_EH    33824                     // ushort[32][1024][8] = 131072 floats
#define W_EL    164896                    // ushort[32][1024][8]
#define W_CBT   33824                     // cbT[256][1024] f32, ALIASES Eh/El
                                          // (dead after vq_main; written by
                                          // vq_epi, read by vq_refine)
#define W_V1    295968                    // + 262144 (8 chunks x 32768 tok)
#define W_V2    558112                    // + 262144
#define W_I1    820256                    // + 262144 (int)
#define W_FLAGS 1082400                   // + 32768 (int)

#define FLAG_EPS 6.5e-5f   // 2 ulps at mag 512: covers 1-ulp-per-value drift

__device__ __forceinline__ unsigned bf16rne(float f) {
    const unsigned u = __float_as_uint(f);
    return (u + 0x7FFFu + ((u >> 16) & 1u)) >> 16;
}

// inline-asm 16B load: invisible to LLVM's load-sinking -> stays where issued
template<int OFF>
__device__ __forceinline__ bf16x8 ld128(const unsigned short* p) {
    bf16x8 r;
    asm volatile("global_load_dwordx4 %0, %1, off offset:%2"
                 : "=&v"(r) : "v"(p), "i"(OFF));
    return r;
}
#define VMWAIT16 asm volatile("s_waitcnt vmcnt(16)")
#define VMWAIT0  asm volatile("s_waitcnt vmcnt(0)")
#define SB0 __builtin_amdgcn_sched_barrier(0)

// ---------------------------------------------------------------- prep ------
// blocks 0..63: eNorm (EXACT R5-R9 order) + Eh/El bf16-split planes in
// octet-major [d/8][cand][8] layout + zeroing.
// blocks 64..319: A[n] = ||x_n||^2 serial fmaf ascending c (BIT-IDENTICAL to
// R3-R9's proven order), one thread per token, fused with the Xh/Xl bf16
// split planes written octet-major [d/8][tok][8] into out-scratch.
// R21: 2 active waves per x-block (waves 2-3 exit) -> all 256 CUs used.
__global__ __launch_bounds__(256) void vq_prep(const float* __restrict__ cb,
                                               const float* __restrict__ x,
                                               float* __restrict__ ws,
                                               float* __restrict__ out) {
    const int t = threadIdx.x;
    if (blockIdx.x < 64) {
        __shared__ float tile[256][17];
        const int k0 = blockIdx.x * 16;
        #pragma unroll
        for (int i = 0; i < 16; ++i)
            tile[t][i] = cb[(size_t)(k0 + i) * D_EMB + t];   // coalesced
        __syncthreads();
        {   // eNorm: 4 rows/wave, 16 lanes x 16 serial d's + shfl tree
            const int i = t >> 4, j = t & 15;
            float s = 0.0f;
            #pragma unroll
            for (int m = 0; m < 16; ++m) {
                const float v = tile[j * 16 + m][i];
                s = fmaf(v, v, s);
            }
            #pragma unroll
            for (int off = 8; off > 0; off >>= 1) s += __shfl_down(s, off);
            if (j == 0) ws[W_ENORM + k0 + i] = s;
        }
        {   // bf16 hi/lo split planes of E, octet-major [d/8][cand][8]
            unsigned short* __restrict__ Ehp = (unsigned short*)(ws + W_EH);
            unsigned short* __restrict__ Elp = (unsigned short*)(ws + W_EL);
            const int oct = t >> 3, d7 = t & 7;
            #pragma unroll
            for (int i = 0; i < 16; ++i) {
                const float v = tile[t][i];
                const unsigned h = bf16rne(v);
                const unsigned l = bf16rne(v - __uint_as_float(h << 16));
                const size_t off = ((size_t)oct * K_EMB + (k0 + i)) * 8 + d7;
                Ehp[off] = (unsigned short)h;
                Elp[off] = (unsigned short)l;
            }
        }
        if (blockIdx.x == 0 && t == 0) *(double*)(ws + W_LOSS) = 0.0;
        if (blockIdx.x == 0 && t == 1) ((int*)ws)[W_CNT] = 0;
    } else {
        if (t >= 128) return;               // waves 2-3 idle (no barriers)
        const int tile4 = (blockIdx.x - 64) * 2 + (t >> 6);  // 0..511
        const int b     = tile4 >> 4;
        const int hw0   = (tile4 & 15) * 64;
        const int tok   = t & 63;
        const int n     = tile4 * 64 + tok;
        const float* __restrict__ xb = x + (size_t)b * CHW + hw0 + tok;
        unsigned short* __restrict__ XhG =
            (unsigned short*)(out + O_SCRATCH);
        unsigned short* __restrict__ XlG = XhG + XPLANE_USHORTS;
        float a = 0.0f;
        #pragma unroll 16
        for (int c8 = 0; c8 < 32; ++c8) {
            unsigned hh[8], ll[8];
            #pragma unroll
            for (int j = 0; j < 8; ++j) {
                const float v = xb[(size_t)(c8 * 8 + j) * HW_SZ];
                a = fmaf(v, v, a);               // same ascending-c order
                const unsigned h = bf16rne(v);
                hh[j] = h;
                ll[j] = bf16rne(v - __uint_as_float(h << 16));
            }
            uint4 ph, pl;
            ph.x = hh[0] | (hh[1] << 16); ph.y = hh[2] | (hh[3] << 16);
            ph.z = hh[4] | (hh[5] << 16); ph.w = hh[6] | (hh[7] << 16);
            pl.x = ll[0] | (ll[1] << 16); pl.y = ll[2] | (ll[3] << 16);
            pl.z = ll[4] | (ll[5] << 16); pl.w = ll[6] | (ll[7] << 16);
            *(uint4*)&XhG[((size_t)c8 * 32768 + n) * 8] = ph;
            *(uint4*)&XlG[((size_t)c8 * 32768 + n) * 8] = pl;
        }
        ws[W_A + n] = a;
    }
}

// ---------------------------------------------------------------- main ------
// Block: 128 tok x 128 cand (kc chunk 0..7), K=256 in 8 BK=32 iters.
// Wave quadrants 64x64; per wave 4x4 mfma_f32_16x16x32_bf16 tiles, 3 products.
// R17 inner loop (asm-load 2-deep ping-pong, counted vmcnt) FROZEN.
// R19 XCD swizzle kept (g%8 == mt%8).
__global__ __launch_bounds__(256, 2) void vq_main(float* __restrict__ ws,
                                                  const float* __restrict__ out) {
    const int g   = blockIdx.x;
    const int kc  = (g >> 3) & 7;           // candidate chunk (128 cands)
    const int mt  = (g & 7) | ((g >> 6) << 3);  // token tile (128 tokens)
    const int n0  = mt * 128;
    const int t   = threadIdx.x;
    const int lane = t & 63, w = t >> 6;
    const int l15 = lane & 15, q = lane >> 4;
    const int tokB  = (w & 1) * 64;
    const int candB = (w >> 1) * 64;
    const int cg    = w >> 1;

    __shared__ float mv1[2][128], mv2[2][128];
    __shared__ int   mi1[2][128];

    const unsigned short* __restrict__ XhG =
        (const unsigned short*)(out + O_SCRATCH);
    const unsigned short* __restrict__ XlG = XhG + XPLANE_USHORTS;
    const unsigned short* __restrict__ EhG = (const unsigned short*)(ws + W_EH);
    const unsigned short* __restrict__ ElG = (const unsigned short*)(ws + W_EL);

    f32x4 acc[4][4];
    #pragma unroll
    for (int mi = 0; mi < 4; ++mi)
        #pragma unroll
        for (int ni = 0; ni < 4; ++ni) acc[mi][ni] = (f32x4){0.f, 0.f, 0.f, 0.f};

    // per-lane fragment base offsets (ushort units); rows are 8 ushorts = 16B
    const size_t xoff = ((size_t)q * 32768 + n0 + tokB + l15) * 8;
    const size_t eoff = ((size_t)q * 1024 + (size_t)kc * 128 + candB + l15) * 8;

    // two named fragment sets (ping-pong)
    bf16x8 ahA[4], alA[4], bhA[4], blA[4];
    bf16x8 ahB[4], alB[4], bhB[4], blB[4];

    auto LD = [&](bf16x8* ah, bf16x8* al, bf16x8* bh, bf16x8* bl, int kt) {
        const unsigned short* ph = XhG + xoff + (size_t)kt * (4 * 32768 * 8);
        const unsigned short* pl = XlG + xoff + (size_t)kt * (4 * 32768 * 8);
        const unsigned short* qh = EhG + eoff + (size_t)kt * (4 * 1024 * 8);
        const unsigned short* ql = ElG + eoff + (size_t)kt * (4 * 1024 * 8);
        ah[0] = ld128<0>(ph);   ah[1] = ld128<256>(ph);
        ah[2] = ld128<512>(ph); ah[3] = ld128<768>(ph);
        al[0] = ld128<0>(pl);   al[1] = ld128<256>(pl);
        al[2] = ld128<512>(pl); al[3] = ld128<768>(pl);
        bh[0] = ld128<0>(qh);   bh[1] = ld128<256>(qh);
        bh[2] = ld128<512>(qh); bh[3] = ld128<768>(qh);
        bl[0] = ld128<0>(ql);   bl[1] = ld128<256>(ql);
        bl[2] = ld128<512>(ql); bl[3] = ld128<768>(ql);
    };
    auto MMA = [&](const bf16x8* ah, const bf16x8* al,
                   const bf16x8* bh, const bf16x8* bl) {
        #pragma unroll
        for (int mi = 0; mi < 4; ++mi)
            #pragma unroll
            for (int ni = 0; ni < 4; ++ni) {
                acc[mi][ni] = __builtin_amdgcn_mfma_f32_16x16x32_bf16(
                    ah[mi], bh[ni], acc[mi][ni], 0, 0, 0);
                acc[mi][ni] = __builtin_amdgcn_mfma_f32_16x16x32_bf16(
                    ah[mi], bl[ni], acc[mi][ni], 0, 0, 0);
                acc[mi][ni] = __builtin_amdgcn_mfma_f32_16x16x32_bf16(
                    al[mi], bh[ni], acc[mi][ni], 0, 0, 0);
            }
    };

    LD(ahA, alA, bhA, blA, 0);               // prologue: 16 in flight
    #pragma unroll
    for (int kt = 0; kt < 8; kt += 2) {
        LD(ahB, alB, bhB, blB, kt + 1);      // 32 in flight
        VMWAIT16; SB0;                       // A(kt) complete, B in flight
        MMA(ahA, alA, bhA, blA); SB0;        // compute even kt
        if (kt + 2 < 8) {
            LD(ahA, alA, bhA, blA, kt + 2);  // 32 in flight
            VMWAIT16;                        // B(kt+1) complete
        } else {
            VMWAIT0;                         // last pair: drain
        }
        SB0;
        MMA(ahB, alB, bhB, blB); SB0;        // compute odd kt
    }

    // epilogue: r = fl(fl(A+B)-2D'); per-lane top-2 over ni, xor-butterfly
    // over l15, then 2-half merge (first-index ties preserved throughout).
    float env[4];
    #pragma unroll
    for (int ni = 0; ni < 4; ++ni)
        env[ni] = ws[W_ENORM + kc * 128 + candB + ni * 16 + l15];
    #pragma unroll
    for (int mi = 0; mi < 4; ++mi) {
        const f32x4 A4 = *(const f32x4*)&ws[W_A + n0 + tokB + mi * 16 + q * 4];
        #pragma unroll
        for (int r = 0; r < 4; ++r) {
            const float a = A4[r];
            float v1 = 3.4e38f, v2 = 3.4e38f;
            int i1 = 0;
            #pragma unroll
            for (int ni = 0; ni < 4; ++ni) {   // ascending cand id
                const float vv = __fsub_rn(__fadd_rn(a, env[ni]),
                                           __fmul_rn(2.0f, acc[mi][ni][r]));
                const int id = kc * 128 + candB + ni * 16 + l15;
                if (vv < v1) { v2 = v1; v1 = vv; i1 = id; }
                else if (vv < v2) { v2 = vv; }
            }
            #pragma unroll
            for (int s = 1; s < 16; s <<= 1) {
                const float ov1 = __shfl_xor(v1, s);
                const float ov2 = __shfl_xor(v2, s);
                const int   oi1 = __shfl_xor(i1, s);
                const bool owin = (ov1 < v1) || (ov1 == v1 && oi1 < i1);
                const float lose = owin ? v1 : ov1;
                const float wsec = owin ? ov2 : v2;
                v1 = owin ? ov1 : v1;
                i1 = owin ? oi1 : i1;
                v2 = fminf(lose, wsec);
            }
            if (l15 == 0) {
                const int tok = tokB + mi * 16 + q * 4 + r;
                mv1[cg][tok] = v1;
                mv2[cg][tok] = v2;
                mi1[cg][tok] = i1;
            }
        }
    }
    __syncthreads();
    if (t < 128) {   // merge the 2 cand-halves (cg0 ids < cg1 ids on ties)
        const float a1 = mv1[0][t], a2 = mv2[0][t];
        const float b1 = mv1[1][t], b2 = mv2[1][t];
        const int   ia = mi1[0][t], ib = mi1[1][t];
        const bool bwin = (b1 < a1);        // tie -> a (smaller ids) wins
        const float best = bwin ? b1 : a1;
        const int   bi   = bwin ? ib : ia;
        const float sec  = fminf(bwin ? a1 : b1, bwin ? b2 : a2);
        const int slot = kc * 32768 + n0 + t;
        ws[W_V1 + slot] = best;
        ws[W_V2 + slot] = sec;
        ((int*)ws)[W_I1 + slot] = bi;
    }
}

// ---------------------------------------------------------------- epi -------
// blocks 0..511:   merge 8 chunk top-2s (flags + loss + idx) + quantized.
// blocks 512..575: cbT transpose into ws[W_CBT] for vq_refine.
// blocks 576..1087: one-hot, idx re-derived from ws V1/I1 (merge-lite with
//                   identical tie rules; race-free: reads vq_main output).
__global__ __launch_bounds__(256) void vq_epi(const float* __restrict__ x,
                                              const float* __restrict__ cb,
                                              float* __restrict__ ws,
                                              float* __restrict__ out) {
    (void)x;
    const int bid = blockIdx.x;
    const int t   = threadIdx.x;

    if (bid >= 576) {                       // ---- one-hot blocks ----
        const int tile = bid - 576;         // 0..511
        const int n0   = tile * 64;
        __shared__ int idxS[64];
        if (t < 64) {                       // merge-lite: same tie rules
            float best = 3.4e38f;
            int bi = 0;
            for (int kc = 0; kc < 8; ++kc) {
                const int slot = kc * 32768 + n0 + t;
                const float v = ws[W_V1 + slot];
                const int  id = ((const int*)ws)[W_I1 + slot];
                if (v < best || (v == best && id < bi)) { best = v; bi = id; }
            }
            idxS[t] = bi;
        }
        __syncthreads();
        float* encp = out + O_ENC + (size_t)n0 * K_EMB;
        const int c0 = t * 4;
        for (int row = 0; row < 64; ++row) {
            const int id = idxS[row];
            f32x4 ev;
            ev[0] = (c0     == id) ? 1.0f : 0.0f;
            ev[1] = (c0 + 1 == id) ? 1.0f : 0.0f;
            ev[2] = (c0 + 2 == id) ? 1.0f : 0.0f;
            ev[3] = (c0 + 3 == id) ? 1.0f : 0.0f;
            *(f32x4*)&encp[row * K_EMB + c0] = ev;
        }
        return;
    }

    if (bid >= 512) {                       // ---- cbT transpose blocks ----
        __shared__ float tt[16][257];
        const int k0 = (bid - 512) * 16;
        #pragma unroll
        for (int i = 0; i < 16; ++i)
            tt[i][t] = cb[(size_t)(k0 + i) * D_EMB + t];   // coalesced
        __syncthreads();
        float* __restrict__ cbT = ws + W_CBT;
        const int j = t & 15;               // cand within chunk
        #pragma unroll
        for (int dd = t >> 4; dd < 256; dd += 16)
            cbT[(size_t)dd * K_EMB + k0 + j] = tt[j][dd];
        return;
    }

    // ---- merge + quantized blocks ----
    const int tile = bid;                   // 0..511 (64-token tiles)
    const int b    = tile >> 4;
    const int hw0  = (tile & 15) * 64;
    const int n0   = tile * 64;

    __shared__ float qs[32 * 65];           // 8.3KB (bank-conflict pad)
    __shared__ int   idxS[64];

    if (t < 64) {
        float best = 3.4e38f, sec = 3.4e38f, bv2 = 3.4e38f;
        int bi = 0;
        for (int kc = 0; kc < 8; ++kc) {    // ascending kc => ascending ids
            const int slot = kc * 32768 + n0 + t;
            const float v  = ws[W_V1 + slot];
            const float v2 = ws[W_V2 + slot];
            const int  id  = ((const int*)ws)[W_I1 + slot];
            if (v < best || (v == best && id < bi)) {
                if (best < sec) sec = best;
                best = v; bi = id; bv2 = v2;
            } else if (v < sec) { sec = v; }
        }
        if (bv2 < sec) sec = bv2;
        idxS[t] = bi;
        out[O_IDX + n0 + t] = (float)bi;
        if (sec - best <= FLAG_EPS) {       // near-tie: fp64 re-decision
            const int p = atomicAdd((int*)ws + W_CNT, 1);
            ((int*)ws)[W_FLAGS + p] = n0 + t;
        }
        // loss partial: sum of best distances over this tile (wave 0 only)
        float ls = best;
        #pragma unroll
        for (int off = 32; off > 0; off >>= 1) ls += __shfl_down(ls, off);
        if (t == 0) atomicAdd((double*)(ws + W_LOSS), (double)ls);
    }

    // quantized (= straight-through value)
    for (int cc = 0; cc < 256; cc += 32) {
        __syncthreads();
        {   // gather 64 codebook rows' 32-col slice into LDS, transposed
            const int r = t >> 2, part = t & 3;
            const float* crow = cb + (size_t)idxS[r] * D_EMB + cc + part * 8;
            const float4 q0 = *(const float4*)(crow);
            const float4 q1 = *(const float4*)(crow + 4);
            const int cb0 = part * 8;
            qs[(cb0 + 0) * 65 + r] = q0.x; qs[(cb0 + 1) * 65 + r] = q0.y;
            qs[(cb0 + 2) * 65 + r] = q0.z; qs[(cb0 + 3) * 65 + r] = q0.w;
            qs[(cb0 + 4) * 65 + r] = q1.x; qs[(cb0 + 5) * 65 + r] = q1.y;
            qs[(cb0 + 6) * 65 + r] = q1.z; qs[(cb0 + 7) * 65 + r] = q1.w;
        }
        __syncthreads();
        const int tok = t & 63, cgr = t >> 6;
        #pragma unroll
        for (int m = 0; m < 8; ++m) {
            const int cl = cgr * 8 + m;
            const int c  = cc + cl;
            out[O_QUANT + (size_t)b * CHW + (size_t)c * HW_SZ + hw0 + tok] =
                qs[cl * 65 + tok];
        }
    }
}

// --------------------------------------------------------------- refine -----
// One token per block, one candidate per thread (1024): fp64 dot via
// coalesced cbT (same ascending-d order -> bit-identical), np op-order
// fp32 rounding, lexicographic (r,k) tree reduce; patch idx/one-hot/
// quantized; writes final loss.
__global__ __launch_bounds__(1024) void vq_refine(const float* __restrict__ x,
                                                  const float* __restrict__ cb,
                                                  const float* __restrict__ ws,
                                                  float* __restrict__ out) {
    if (blockIdx.x == 0 && threadIdx.x == 0)
        out[0] = (float)(1.25 * (*(const double*)(ws + W_LOSS)) / 8388608.0);
    __shared__ float xs[256];
    __shared__ float rS[1024];
    __shared__ int   kS[1024];
    int cnt = ((const int*)ws)[W_CNT];
    if (cnt > 32768) cnt = 32768;
    const int t = threadIdx.x;
    const float* __restrict__ eN  = ws + W_ENORM;
    const float* __restrict__ cbT = ws + W_CBT;
    for (int fi = blockIdx.x; fi < cnt; fi += gridDim.x) {
        const int n  = ((const int*)ws)[W_FLAGS + fi];
        const int b  = n >> 10;
        const int hw = n & 1023;
        __syncthreads();   // protect xs/rS/kS reuse across fi iterations
        if (t < 256) xs[t] = x[(size_t)b * CHW + (size_t)t * HW_SZ + hw];
        __syncthreads();
        const float A = ws[W_A + n];        // same A as vq_main used
        {
            const int k = t;                // one candidate per thread
            double d64 = 0.0;
            #pragma unroll 8
            for (int d = 0; d < 256; ++d)
                d64 = fma((double)cbT[(size_t)d * K_EMB + k],
                          (double)xs[d], d64);
            const float M  = (float)d64;    // ideal np matmul output
            const float T1 = __fadd_rn(A, eN[k]);
            rS[t] = __fsub_rn(T1, __fmul_rn(2.0f, M));
            kS[t] = k;
        }
        __syncthreads();
        for (int off = 512; off > 0; off >>= 1) {
            if (t < off) {
                const float r = rS[t + off]; const int id = kS[t + off];
                if (r < rS[t] || (r == rS[t] && id < kS[t])) {
                    rS[t] = r; kS[t] = id;  // lexicographic (r, k)
                }
            }
            __syncthreads();
        }
        const int newIdx = kS[0];
        if (t == 0) {
            const int oldIdx = (int)out[O_IDX + n];
            out[O_IDX + n] = (float)newIdx;
            out[O_ENC + (size_t)n * K_EMB + oldIdx] = 0.0f;  // same thread:
            out[O_ENC + (size_t)n * K_EMB + newIdx] = 1.0f;  // ordered stores
        }
        if (t < 256)
            out[O_QUANT + (size_t)b * CHW + (size_t)t * HW_SZ + hw] =
                cb[(size_t)newIdx * D_EMB + t];
    }
}

extern "C" void kernel_launch(void* const* d_in, const int* in_sizes, int n_in,
                              void* d_out, int out_size, void* d_ws, size_t ws_size,
                              hipStream_t stream) {
    (void)in_sizes; (void)n_in; (void)out_size; (void)ws_size;
    const float* x  = (const float*)d_in[0];
    const float* cb = (const float*)d_in[1];
    float* out = (float*)d_out;
    float* ws  = (float*)d_ws;
    hipLaunchKernelGGL(vq_prep,   dim3(320),  dim3(256),  0, stream, cb, x, ws, out);
    hipLaunchKernelGGL(vq_main,   dim3(2048), dim3(256),  0, stream, ws, out);
    hipLaunchKernelGGL(vq_epi,    dim3(1088), dim3(256),  0, stream, x, cb, ws, out);
    hipLaunchKernelGGL(vq_refine, dim3(1024), dim3(1024), 0, stream, x, cb, ws, out);
}